// Round 7
// baseline (471.345 us; speedup 1.0000x reference)
//
#include <hip/hip_runtime.h>
#include <math.h>

#define B_   32
#define L_   256
#define S_   64
#define D_   128
#define H_   4
#define DH_  32
#define NTOK (B_*L_)   // 8192

// ws layout: qk[NTOK][4][128] f32 | cbias[NTOK][4] f32 | ctx[NTOK][128] f32
#define QK_OFF   0
#define QK_BYTES ((size_t)NTOK*512*4)
#define CB_OFF   (QK_OFF + QK_BYTES)
#define CB_BYTES ((size_t)NTOK*4*4)
#define CTX_OFF  (CB_OFF + CB_BYTES)

// ---------------------------------------------------------------------------
// Kernel B: per token  q = qw x + qb ;  qk_h = scale*kw_h^T q_h ;
//           cbias_h = scale * q_h . kb_h      (32 tokens/block, 256 thr)
// ---------------------------------------------------------------------------
__global__ __launch_bounds__(256) void qk_kernel(
        const float* __restrict__ h_wq,
        const float* __restrict__ in_proj_w, const float* __restrict__ in_proj_b,
        float* __restrict__ qk_out, float* __restrict__ cb_out) {
    __shared__ float x_lds[32*128];
    __shared__ float q_lds[32*128];
    const int t0 = blockIdx.x * 32;
    const int tid = threadIdx.x;

    { // stage 32 token rows of h_wq
        const float4* src = (const float4*)(h_wq + (size_t)t0*128);
        float4* dst = (float4*)x_lds;
        for (int e = tid; e < 32*32; e += 256) dst[e] = src[e];
    }
    __syncthreads();

    const int d = tid & 127, half = tid >> 7;
    const float* xb = x_lds + half*16*128;
    { // Q projection
        float acc[16];
        const float qb = in_proj_b[d];
        #pragma unroll
        for (int t = 0; t < 16; ++t) acc[t] = qb;
        const float4* wrow = (const float4*)(in_proj_w + (size_t)d*128);
        for (int j4 = 0; j4 < 32; ++j4) {
            float4 w = wrow[j4];
            #pragma unroll
            for (int t = 0; t < 16; ++t) {
                float4 x = *(const float4*)(xb + t*128 + j4*4);
                acc[t] += w.x*x.x + w.y*x.y + w.z*x.z + w.w*x.w;
            }
        }
        #pragma unroll
        for (int t = 0; t < 16; ++t) q_lds[(half*16+t)*128 + d] = acc[t];
    }
    __syncthreads();

    const float scale = 0.17677669529663687f;  // 1/sqrt(32)
    const float* qbse = q_lds + half*16*128;
    #pragma unroll
    for (int h = 0; h < 4; ++h) {   // qk_h[d], coalesced kw column access
        float acc[16];
        #pragma unroll
        for (int t = 0; t < 16; ++t) acc[t] = 0.f;
        for (int j = 0; j < 32; ++j) {
            float w = in_proj_w[(size_t)(128 + h*32 + j)*128 + d];
            #pragma unroll
            for (int t = 0; t < 16; ++t) acc[t] += w * qbse[t*128 + h*32 + j];
        }
        #pragma unroll
        for (int t = 0; t < 16; ++t)
            qk_out[(size_t)(t0 + half*16 + t)*512 + h*128 + d] = acc[t] * scale;
    }
    if (tid < 128) { // cbias
        int t = tid >> 2, h = tid & 3;
        float s = 0.f;
        for (int j = 0; j < 32; ++j)
            s += q_lds[t*128 + h*32 + j] * in_proj_b[128 + h*32 + j];
        cb_out[(t0 + t)*4 + h] = s * scale;
    }
}

// ---------------------------------------------------------------------------
// Kernel C: SINGLE-PASS online-softmax attention. 4 tokens/block (one 64-lane
// wave per token), lane owns d = 2*lane, 2*lane+1. Each allowed row is read
// from global exactly ONCE (float2, coalesced 512B/wave); per row: 4 head-dot
// partials -> one 6-step shfl_xor butterfly (4 heads together) -> online
// max/sum rescale of per-lane u accumulators. No score LDS, no row re-read
// (R6 re-read missed L2: 14MB/XCD working set vs 4MB -> ~2x HBM).
// Then cooperative ctx phase: each vw row read ONCE per block for 4 tokens.
// ---------------------------------------------------------------------------
__global__ __launch_bounds__(256) void attn_kernel(
        const float* __restrict__ h_all,
        const float* __restrict__ in_proj_w, const float* __restrict__ in_proj_b,
        const float* __restrict__ qk_buf, const float* __restrict__ cb_buf,
        const int* __restrict__ station_id, const float* __restrict__ adj,
        float* __restrict__ ctx_out) {
    __shared__ float u_lds[4][4*132];   // [tok][h*132 + d], stride-132 pad
    __shared__ int   lst[64];
    __shared__ int   cnt_s;

    const int t0  = blockIdx.x * 4;      // 4 tokens, same b (4 | 256)
    const int b   = t0 >> 8;
    const int tid = threadIdx.x;
    const int wv  = tid >> 6;            // token slot 0..3
    const int lane = tid & 63;
    const int t = t0 + wv;

    if (tid < 64) { // wave 0: allowed-mask ballot -> compacted list
        int sid = station_id[b];
        int s = tid;
        bool av = (adj[sid*S_ + s] > 0.0f) && (s != sid);
        unsigned long long m = __ballot(av);
        if (m == 0ull) { av = (s != sid); m = __ballot(av); }   // all-but-self
        if (m == 0ull) { av = (s == sid); m = __ballot(av); }   // S==1 safety
        int idx = __popcll(m & ((1ull << s) - 1ull));
        if (av) lst[idx] = s;
        if (s == 0) cnt_s = __popcll(m);
    }

    // per-lane qk fragment (registers, no LDS): qk_h[2*lane], qk_h[2*lane+1]
    const float* qkt = qk_buf + (size_t)t*512 + 2*lane;
    const float2 qk0 = *(const float2*)(qkt);
    const float2 qk1 = *(const float2*)(qkt + 128);
    const float2 qk2 = *(const float2*)(qkt + 256);
    const float2 qk3 = *(const float2*)(qkt + 384);
    const float cb0 = cb_buf[t*4+0], cb1 = cb_buf[t*4+1];
    const float cb2 = cb_buf[t*4+2], cb3 = cb_buf[t*4+3];

    __syncthreads();               // publish lst/cnt
    const int cnt = cnt_s;
    const float* rowbase = h_all + (size_t)t * (S_*D_) + 2*lane;

    float m0 = -INFINITY, m1 = -INFINITY, m2 = -INFINITY, m3 = -INFINITY;
    float l0 = 0.f, l1 = 0.f, l2 = 0.f, l3 = 0.f;
    float2 u0 = {0.f,0.f}, u1 = {0.f,0.f}, u2 = {0.f,0.f}, u3 = {0.f,0.f};

    for (int i = 0; i < cnt; ++i) {
        float2 x = *(const float2*)(rowbase + lst[i]*D_);
        float p0 = qk0.x*x.x + qk0.y*x.y;
        float p1 = qk1.x*x.x + qk1.y*x.y;
        float p2 = qk2.x*x.x + qk2.y*x.y;
        float p3 = qk3.x*x.x + qk3.y*x.y;
        #pragma unroll
        for (int o = 32; o >= 1; o >>= 1) {   // 64-lane butterfly, 4 heads
            p0 += __shfl_xor(p0, o);
            p1 += __shfl_xor(p1, o);
            p2 += __shfl_xor(p2, o);
            p3 += __shfl_xor(p3, o);
        }
        float s0 = p0 + cb0, s1 = p1 + cb1, s2 = p2 + cb2, s3 = p3 + cb3;
        // online softmax update, head 0..3 (branch-free; s uniform per wave)
        float n0 = fmaxf(m0, s0), r0 = __expf(m0 - n0), w0 = __expf(s0 - n0);
        l0 = l0*r0 + w0; u0.x = u0.x*r0 + w0*x.x; u0.y = u0.y*r0 + w0*x.y; m0 = n0;
        float n1 = fmaxf(m1, s1), r1 = __expf(m1 - n1), w1 = __expf(s1 - n1);
        l1 = l1*r1 + w1; u1.x = u1.x*r1 + w1*x.x; u1.y = u1.y*r1 + w1*x.y; m1 = n1;
        float n2 = fmaxf(m2, s2), r2 = __expf(m2 - n2), w2 = __expf(s2 - n2);
        l2 = l2*r2 + w2; u2.x = u2.x*r2 + w2*x.x; u2.y = u2.y*r2 + w2*x.y; m2 = n2;
        float n3 = fmaxf(m3, s3), r3 = __expf(m3 - n3), w3 = __expf(s3 - n3);
        l3 = l3*r3 + w3; u3.x = u3.x*r3 + w3*x.x; u3.y = u3.y*r3 + w3*x.y; m3 = n3;
    }
    {
        float i0 = 1.f/l0, i1 = 1.f/l1, i2 = 1.f/l2, i3 = 1.f/l3;
        u0.x *= i0; u0.y *= i0;  u1.x *= i1; u1.y *= i1;
        u2.x *= i2; u2.y *= i2;  u3.x *= i3; u3.y *= i3;
        *(float2*)&u_lds[wv][0*132 + 2*lane] = u0;
        *(float2*)&u_lds[wv][1*132 + 2*lane] = u1;
        *(float2*)&u_lds[wv][2*132 + 2*lane] = u2;
        *(float2*)&u_lds[wv][3*132 + 2*lane] = u3;
    }
    __syncthreads();

    if (tid < 128) { // ctx for all 4 tokens; vw row read ONCE per block
        const int d = tid, h = d >> 5;
        const float4* vwrow = (const float4*)(in_proj_w + (size_t)(256 + d)*128);
        const float vb = in_proj_b[256 + d];
        float a0 = vb, a1 = vb, a2 = vb, a3 = vb;
        #pragma unroll 8
        for (int j4 = 0; j4 < 32; ++j4) {
            float4 w = vwrow[j4];
            float4 v0 = *(const float4*)(&u_lds[0][h*132 + j4*4]);
            float4 v1 = *(const float4*)(&u_lds[1][h*132 + j4*4]);
            float4 v2 = *(const float4*)(&u_lds[2][h*132 + j4*4]);
            float4 v3 = *(const float4*)(&u_lds[3][h*132 + j4*4]);
            a0 += w.x*v0.x + w.y*v0.y + w.z*v0.z + w.w*v0.w;
            a1 += w.x*v1.x + w.y*v1.y + w.z*v1.z + w.w*v1.w;
            a2 += w.x*v2.x + w.y*v2.y + w.z*v2.z + w.w*v2.w;
            a3 += w.x*v3.x + w.y*v3.y + w.z*v3.z + w.w*v3.w;
        }
        ctx_out[(size_t)(t0+0)*128 + d] = a0;
        ctx_out[(size_t)(t0+1)*128 + d] = a1;
        ctx_out[(size_t)(t0+2)*128 + d] = a2;
        ctx_out[(size_t)(t0+3)*128 + d] = a3;
    }
}

// ---------------------------------------------------------------------------
// Kernel D: out-proj + gate + residual + LayerNorm. 32 tokens/block, 256 thr.
// ---------------------------------------------------------------------------
__global__ __launch_bounds__(256) void epi_kernel(
        const float* __restrict__ h_wq, const float* __restrict__ ctx_buf,
        const float* __restrict__ out_w, const float* __restrict__ out_b,
        const float* __restrict__ gate_w, const float* __restrict__ gate_b,
        const float* __restrict__ ln_g, const float* __restrict__ ln_b,
        const float* __restrict__ alpha, float* __restrict__ out) {
    __shared__ float c_tile[32*128];  // ctx, later y
    __shared__ float x_tile[32*128];
    __shared__ float o_tile[32*128];
    __shared__ float mu_s[32], rs_s[32];
    const int t0 = blockIdx.x * 32;
    const int tid = threadIdx.x;

    {
        const float4* cs = (const float4*)(ctx_buf + (size_t)t0*128);
        const float4* xs = (const float4*)(h_wq + (size_t)t0*128);
        float4* cd = (float4*)c_tile; float4* xd = (float4*)x_tile;
        for (int e = tid; e < 32*32; e += 256) { cd[e] = cs[e]; xd[e] = xs[e]; }
    }
    __syncthreads();

    const int d = tid & 127, half = tid >> 7;
    float o_acc[16];
    { // out-proj
        const float ob = out_b[d];
        #pragma unroll
        for (int t = 0; t < 16; ++t) o_acc[t] = ob;
        const float4* wrow = (const float4*)(out_w + (size_t)d*128);
        const float* cbp = c_tile + half*16*128;
        for (int j4 = 0; j4 < 32; ++j4) {
            float4 w = wrow[j4];
            #pragma unroll
            for (int t = 0; t < 16; ++t) {
                float4 c = *(const float4*)(cbp + t*128 + j4*4);
                o_acc[t] += w.x*c.x + w.y*c.y + w.z*c.z + w.w*c.w;
            }
        }
        #pragma unroll
        for (int t = 0; t < 16; ++t) o_tile[(half*16+t)*128 + d] = o_acc[t];
    }
    __syncthreads();

    { // gate + residual, write y into c_tile
        float g_acc[16];
        const float gb = gate_b[d];
        #pragma unroll
        for (int t = 0; t < 16; ++t) g_acc[t] = gb;
        const float4* wrow = (const float4*)(gate_w + (size_t)d*256);
        const float* xb = x_tile + half*16*128;
        const float* obp = o_tile + half*16*128;
        for (int j4 = 0; j4 < 32; ++j4) {
            float4 w0 = wrow[j4];
            float4 w1 = wrow[32 + j4];
            #pragma unroll
            for (int t = 0; t < 16; ++t) {
                float4 x = *(const float4*)(xb  + t*128 + j4*4);
                float4 o = *(const float4*)(obp + t*128 + j4*4);
                g_acc[t] += w0.x*x.x + w0.y*x.y + w0.z*x.z + w0.w*x.w
                          + w1.x*o.x + w1.y*o.y + w1.z*o.z + w1.w*o.w;
            }
        }
        const float al = alpha[0];
        #pragma unroll
        for (int t = 0; t < 16; ++t) {
            float g = 1.0f / (1.0f + __expf(-g_acc[t]));
            float y = xb[t*128 + d] + al * g * o_acc[t];
            c_tile[(half*16+t)*128 + d] = y;
        }
    }
    __syncthreads();

    { // LayerNorm stats: 8 lanes per token
        int tt = tid >> 3, k = tid & 7;
        const float* yr = c_tile + tt*128;
        float s = 0.f;
        for (int dd = k; dd < 128; dd += 8) s += yr[dd];
        for (int o = 4; o >= 1; o >>= 1) s += __shfl_xor(s, o, 8);
        float mu = s * (1.0f/128.0f);
        float vs = 0.f;
        for (int dd = k; dd < 128; dd += 8) { float df = yr[dd] - mu; vs += df*df; }
        for (int o = 4; o >= 1; o >>= 1) vs += __shfl_xor(vs, o, 8);
        if (k == 0) { mu_s[tt] = mu; rs_s[tt] = rsqrtf(vs*(1.0f/128.0f) + 1e-5f); }
    }
    __syncthreads();

    for (int e = tid; e < 32*128; e += 256) {
        int tt = e >> 7, dd = e & 127;
        float y = c_tile[e];
        out[(size_t)t0*128 + e] = (y - mu_s[tt]) * rs_s[tt] * ln_g[dd] + ln_b[dd];
    }
}

// ---------------------------------------------------------------------------
extern "C" void kernel_launch(void* const* d_in, const int* in_sizes, int n_in,
                              void* d_out, int out_size, void* d_ws, size_t ws_size,
                              hipStream_t stream) {
    const float* h_wq       = (const float*)d_in[0];
    const float* h_all      = (const float*)d_in[1];
    const int*   station_id = (const int*)  d_in[2];
    const float* adj        = (const float*)d_in[3];
    const float* in_proj_w  = (const float*)d_in[4];
    const float* in_proj_b  = (const float*)d_in[5];
    const float* out_w      = (const float*)d_in[6];
    const float* out_b      = (const float*)d_in[7];
    const float* gate_w     = (const float*)d_in[8];
    const float* gate_b     = (const float*)d_in[9];
    const float* ln_g       = (const float*)d_in[10];
    const float* ln_b       = (const float*)d_in[11];
    const float* alpha      = (const float*)d_in[12];

    char* ws = (char*)d_ws;
    float* qk   = (float*)(ws + QK_OFF);
    float* cb   = (float*)(ws + CB_OFF);
    float* ctx  = (float*)(ws + CTX_OFF);
    float* out  = (float*)d_out;

    qk_kernel  <<<NTOK/32, 256, 0, stream>>>(h_wq, in_proj_w, in_proj_b, qk, cb);
    attn_kernel<<<NTOK/4, 256, 0, stream>>>(h_all, in_proj_w, in_proj_b, qk, cb,
                                            station_id, adj, ctx);
    epi_kernel <<<NTOK/32, 256, 0, stream>>>(h_wq, ctx, out_w, out_b, gate_w,
                                             gate_b, ln_g, ln_b, alpha, out);
}

// Round 9
// 466.251 us; speedup vs baseline: 1.0109x; 1.0109x over previous
//
#include <hip/hip_runtime.h>
#include <math.h>

#define B_   32
#define L_   256
#define S_   64
#define D_   128
#define H_   4
#define DH_  32
#define NTOK (B_*L_)   // 8192

// ws layout: qk[NTOK][4][128] f32 | cbias[NTOK][4] f32 | ctx[NTOK][128] f32
#define QK_OFF   0
#define QK_BYTES ((size_t)NTOK*512*4)
#define CB_OFF   (QK_OFF + QK_BYTES)
#define CB_BYTES ((size_t)NTOK*4*4)
#define CTX_OFF  (CB_OFF + CB_BYTES)

// ---------------------------------------------------------------------------
// Kernel B: per token  q = qw x + qb ;  qk_h = scale*kw_h^T q_h ;
//           cbias_h = scale * q_h . kb_h      (32 tokens/block, 256 thr)
// ---------------------------------------------------------------------------
__global__ __launch_bounds__(256) void qk_kernel(
        const float* __restrict__ h_wq,
        const float* __restrict__ in_proj_w, const float* __restrict__ in_proj_b,
        float* __restrict__ qk_out, float* __restrict__ cb_out) {
    __shared__ float x_lds[32*128];
    __shared__ float q_lds[32*128];
    const int t0 = blockIdx.x * 32;
    const int tid = threadIdx.x;

    { // stage 32 token rows of h_wq
        const float4* src = (const float4*)(h_wq + (size_t)t0*128);
        float4* dst = (float4*)x_lds;
        for (int e = tid; e < 32*32; e += 256) dst[e] = src[e];
    }
    __syncthreads();

    const int d = tid & 127, half = tid >> 7;
    const float* xb = x_lds + half*16*128;
    { // Q projection
        float acc[16];
        const float qb = in_proj_b[d];
        #pragma unroll
        for (int t = 0; t < 16; ++t) acc[t] = qb;
        const float4* wrow = (const float4*)(in_proj_w + (size_t)d*128);
        for (int j4 = 0; j4 < 32; ++j4) {
            float4 w = wrow[j4];
            #pragma unroll
            for (int t = 0; t < 16; ++t) {
                float4 x = *(const float4*)(xb + t*128 + j4*4);
                acc[t] += w.x*x.x + w.y*x.y + w.z*x.z + w.w*x.w;
            }
        }
        #pragma unroll
        for (int t = 0; t < 16; ++t) q_lds[(half*16+t)*128 + d] = acc[t];
    }
    __syncthreads();

    const float scale = 0.17677669529663687f;  // 1/sqrt(32)
    const float* qbse = q_lds + half*16*128;
    #pragma unroll
    for (int h = 0; h < 4; ++h) {   // qk_h[d], coalesced kw column access
        float acc[16];
        #pragma unroll
        for (int t = 0; t < 16; ++t) acc[t] = 0.f;
        for (int j = 0; j < 32; ++j) {
            float w = in_proj_w[(size_t)(128 + h*32 + j)*128 + d];
            #pragma unroll
            for (int t = 0; t < 16; ++t) acc[t] += w * qbse[t*128 + h*32 + j];
        }
        #pragma unroll
        for (int t = 0; t < 16; ++t)
            qk_out[(size_t)(t0 + half*16 + t)*512 + h*128 + d] = acc[t] * scale;
    }
    if (tid < 128) { // cbias
        int t = tid >> 2, h = tid & 3;
        float s = 0.f;
        for (int j = 0; j < 32; ++j)
            s += q_lds[t*128 + h*32 + j] * in_proj_b[128 + h*32 + j];
        cb_out[(t0 + t)*4 + h] = s * scale;
    }
}

// ---------------------------------------------------------------------------
// Kernel C: single-pass online-softmax attention, GROUPED-LANE layout.
// 4 tokens/block, one 64-lane wave per token. The wave's 4 groups of 16 lanes
// each own one head; lane-in-group lg owns elements 8*lg..8*lg+7 of the row.
// Per row: 2 float4 loads (groups alias same lines -> one fetch), 8-FMA dot,
// 4-step width-16 shfl_xor butterfly (ALL heads reduce in parallel: 4 shfls
// per row vs R7's 24), 2 expf, online u/l/m update of the lane's 8-el slice.
// h_all row read exactly once; no score LDS. Then cooperative ctx phase
// using ALL 256 threads (thread = (d, token-pair); 2 dots each).
// ---------------------------------------------------------------------------
__global__ __launch_bounds__(256) void attn_kernel(
        const float* __restrict__ h_all,
        const float* __restrict__ in_proj_w, const float* __restrict__ in_proj_b,
        const float* __restrict__ qk_buf, const float* __restrict__ cb_buf,
        const int* __restrict__ station_id, const float* __restrict__ adj,
        float* __restrict__ ctx_out) {
    __shared__ float u_lds[4][4*132];   // [tok][h*132 + d], stride-132 pad
    __shared__ int   lst[64];
    __shared__ int   cnt_s;

    const int t0  = blockIdx.x * 4;      // 4 tokens, same b (4 | 256)
    const int b   = t0 >> 8;
    const int tid = threadIdx.x;
    const int wv  = tid >> 6;            // token slot 0..3
    const int lane = tid & 63;
    const int g   = lane >> 4;           // head group 0..3
    const int lg  = lane & 15;           // lane in group
    const int t = t0 + wv;

    if (tid < 64) { // wave 0: allowed-mask ballot -> compacted list
        int sid = station_id[b];
        int s = tid;
        bool av = (adj[sid*S_ + s] > 0.0f) && (s != sid);
        unsigned long long m = __ballot(av);
        if (m == 0ull) { av = (s != sid); m = __ballot(av); }   // all-but-self
        if (m == 0ull) { av = (s == sid); m = __ballot(av); }   // S==1 safety
        int idx = __popcll(m & ((1ull << s) - 1ull));
        if (av) lst[idx] = s;
        if (s == 0) cnt_s = __popcll(m);
    }

    // qk fragment for head g, elements 8*lg..8*lg+7 (registers)
    const float* qkp = qk_buf + (size_t)t*512 + g*128 + 8*lg;
    const float4 qa = *(const float4*)(qkp);
    const float4 qb = *(const float4*)(qkp + 4);
    const float cbg = cb_buf[t*4 + g];

    __syncthreads();               // publish lst/cnt
    const int cnt = cnt_s;
    const float* rowbase = h_all + (size_t)t * (S_*D_) + 8*lg;

    float mg = -INFINITY, lsum = 0.f;
    float4 ua = {0.f,0.f,0.f,0.f}, ub = {0.f,0.f,0.f,0.f};

    #pragma unroll 2
    for (int i = 0; i < cnt; ++i) {
        const float* rp = rowbase + lst[i]*D_;
        float4 xa = *(const float4*)(rp);
        float4 xb = *(const float4*)(rp + 4);
        float p = qa.x*xa.x + qa.y*xa.y + qa.z*xa.z + qa.w*xa.w
                + qb.x*xb.x + qb.y*xb.y + qb.z*xb.z + qb.w*xb.w;
        p += __shfl_xor(p, 8, 16);
        p += __shfl_xor(p, 4, 16);
        p += __shfl_xor(p, 2, 16);
        p += __shfl_xor(p, 1, 16);
        float s = p + cbg;                           // uniform within group
        float n = fmaxf(mg, s);
        float r = __expf(mg - n), w = __expf(s - n);
        lsum = lsum*r + w;
        ua.x = ua.x*r + w*xa.x; ua.y = ua.y*r + w*xa.y;
        ua.z = ua.z*r + w*xa.z; ua.w = ua.w*r + w*xa.w;
        ub.x = ub.x*r + w*xb.x; ub.y = ub.y*r + w*xb.y;
        ub.z = ub.z*r + w*xb.z; ub.w = ub.w*r + w*xb.w;
        mg = n;
    }
    {
        float inv = 1.f / lsum;
        ua.x *= inv; ua.y *= inv; ua.z *= inv; ua.w *= inv;
        ub.x *= inv; ub.y *= inv; ub.z *= inv; ub.w *= inv;
        *(float4*)&u_lds[wv][g*132 + 8*lg]     = ua;   // 16B-aligned
        *(float4*)&u_lds[wv][g*132 + 8*lg + 4] = ub;
    }
    __syncthreads();

    { // ctx: ALL 256 threads; thread (d, pair) computes tokens 2p, 2p+1
        const int d = tid & 127, pr = tid >> 7, h = (tid & 127) >> 5;
        const float4* vwrow = (const float4*)(in_proj_w + (size_t)(256 + d)*128);
        const float vb = in_proj_b[256 + d];
        float a0 = vb, a1 = vb;
        const float* uA = &u_lds[2*pr][h*132];
        const float* uB = &u_lds[2*pr+1][h*132];
        #pragma unroll 8
        for (int j4 = 0; j4 < 32; ++j4) {
            float4 w = vwrow[j4];
            float4 v0 = *(const float4*)(uA + j4*4);
            float4 v1 = *(const float4*)(uB + j4*4);
            a0 += w.x*v0.x + w.y*v0.y + w.z*v0.z + w.w*v0.w;
            a1 += w.x*v1.x + w.y*v1.y + w.z*v1.z + w.w*v1.w;
        }
        ctx_out[(size_t)(t0 + 2*pr    )*128 + d] = a0;
        ctx_out[(size_t)(t0 + 2*pr + 1)*128 + d] = a1;
    }
}

// ---------------------------------------------------------------------------
// Kernel D: out-proj + gate + residual + LayerNorm. 32 tokens/block, 256 thr.
// ---------------------------------------------------------------------------
__global__ __launch_bounds__(256) void epi_kernel(
        const float* __restrict__ h_wq, const float* __restrict__ ctx_buf,
        const float* __restrict__ out_w, const float* __restrict__ out_b,
        const float* __restrict__ gate_w, const float* __restrict__ gate_b,
        const float* __restrict__ ln_g, const float* __restrict__ ln_b,
        const float* __restrict__ alpha, float* __restrict__ out) {
    __shared__ float c_tile[32*128];  // ctx, later y
    __shared__ float x_tile[32*128];
    __shared__ float o_tile[32*128];
    __shared__ float mu_s[32], rs_s[32];
    const int t0 = blockIdx.x * 32;
    const int tid = threadIdx.x;

    {
        const float4* cs = (const float4*)(ctx_buf + (size_t)t0*128);
        const float4* xs = (const float4*)(h_wq + (size_t)t0*128);
        float4* cd = (float4*)c_tile; float4* xd = (float4*)x_tile;
        for (int e = tid; e < 32*32; e += 256) { cd[e] = cs[e]; xd[e] = xs[e]; }
    }
    __syncthreads();

    const int d = tid & 127, half = tid >> 7;
    float o_acc[16];
    { // out-proj
        const float ob = out_b[d];
        #pragma unroll
        for (int t = 0; t < 16; ++t) o_acc[t] = ob;
        const float4* wrow = (const float4*)(out_w + (size_t)d*128);
        const float* cbp = c_tile + half*16*128;
        for (int j4 = 0; j4 < 32; ++j4) {
            float4 w = wrow[j4];
            #pragma unroll
            for (int t = 0; t < 16; ++t) {
                float4 c = *(const float4*)(cbp + t*128 + j4*4);
                o_acc[t] += w.x*c.x + w.y*c.y + w.z*c.z + w.w*c.w;
            }
        }
        #pragma unroll
        for (int t = 0; t < 16; ++t) o_tile[(half*16+t)*128 + d] = o_acc[t];
    }
    __syncthreads();

    { // gate + residual, write y into c_tile
        float g_acc[16];
        const float gb = gate_b[d];
        #pragma unroll
        for (int t = 0; t < 16; ++t) g_acc[t] = gb;
        const float4* wrow = (const float4*)(gate_w + (size_t)d*256);
        const float* xb = x_tile + half*16*128;
        const float* obp = o_tile + half*16*128;
        for (int j4 = 0; j4 < 32; ++j4) {
            float4 w0 = wrow[j4];
            float4 w1 = wrow[32 + j4];
            #pragma unroll
            for (int t = 0; t < 16; ++t) {
                float4 x = *(const float4*)(xb  + t*128 + j4*4);
                float4 o = *(const float4*)(obp + t*128 + j4*4);
                g_acc[t] += w0.x*x.x + w0.y*x.y + w0.z*x.z + w0.w*x.w
                          + w1.x*o.x + w1.y*o.y + w1.z*o.z + w1.w*o.w;
            }
        }
        const float al = alpha[0];
        #pragma unroll
        for (int t = 0; t < 16; ++t) {
            float g = 1.0f / (1.0f + __expf(-g_acc[t]));
            float y = xb[t*128 + d] + al * g * o_acc[t];
            c_tile[(half*16+t)*128 + d] = y;
        }
    }
    __syncthreads();

    { // LayerNorm stats: 8 lanes per token
        int tt = tid >> 3, k = tid & 7;
        const float* yr = c_tile + tt*128;
        float s = 0.f;
        for (int dd = k; dd < 128; dd += 8) s += yr[dd];
        for (int o = 4; o >= 1; o >>= 1) s += __shfl_xor(s, o, 8);
        float mu = s * (1.0f/128.0f);
        float vs = 0.f;
        for (int dd = k; dd < 128; dd += 8) { float df = yr[dd] - mu; vs += df*df; }
        for (int o = 4; o >= 1; o >>= 1) vs += __shfl_xor(vs, o, 8);
        if (k == 0) { mu_s[tt] = mu; rs_s[tt] = rsqrtf(vs*(1.0f/128.0f) + 1e-5f); }
    }
    __syncthreads();

    for (int e = tid; e < 32*128; e += 256) {
        int tt = e >> 7, dd = e & 127;
        float y = c_tile[e];
        out[(size_t)t0*128 + e] = (y - mu_s[tt]) * rs_s[tt] * ln_g[dd] + ln_b[dd];
    }
}

// ---------------------------------------------------------------------------
extern "C" void kernel_launch(void* const* d_in, const int* in_sizes, int n_in,
                              void* d_out, int out_size, void* d_ws, size_t ws_size,
                              hipStream_t stream) {
    const float* h_wq       = (const float*)d_in[0];
    const float* h_all      = (const float*)d_in[1];
    const int*   station_id = (const int*)  d_in[2];
    const float* adj        = (const float*)d_in[3];
    const float* in_proj_w  = (const float*)d_in[4];
    const float* in_proj_b  = (const float*)d_in[5];
    const float* out_w      = (const float*)d_in[6];
    const float* out_b      = (const float*)d_in[7];
    const float* gate_w     = (const float*)d_in[8];
    const float* gate_b     = (const float*)d_in[9];
    const float* ln_g       = (const float*)d_in[10];
    const float* ln_b       = (const float*)d_in[11];
    const float* alpha      = (const float*)d_in[12];

    char* ws = (char*)d_ws;
    float* qk   = (float*)(ws + QK_OFF);
    float* cb   = (float*)(ws + CB_OFF);
    float* ctx  = (float*)(ws + CTX_OFF);
    float* out  = (float*)d_out;

    qk_kernel  <<<NTOK/32, 256, 0, stream>>>(h_wq, in_proj_w, in_proj_b, qk, cb);
    attn_kernel<<<NTOK/4, 256, 0, stream>>>(h_all, in_proj_w, in_proj_b, qk, cb,
                                            station_id, adj, ctx);
    epi_kernel <<<NTOK/32, 256, 0, stream>>>(h_wq, ctx, out_w, out_b, gate_w,
                                             gate_b, ln_g, ln_b, alpha, out);
}